// Round 10
// baseline (107.222 us; speedup 1.0000x reference)
//
#include <hip/hip_runtime.h>

#define N_NODES 100000
#define N_EDGES 1000000
#define HIDDEN 64

// ---- geometry ----
#define PAIRS (N_EDGES / 2)              // 500,000 edge pairs
#define N_RANGES 4
#define C_RANGE 25088                    // 4*25088 = 100352 >= 100000; bins 100,352 B LDS
#define N_SLICES 64
#define PPS ((PAIRS + N_SLICES - 1) / N_SLICES)   // 7813 pairs per slice
#define B1_THREADS 512
#define B2_THREADS 1024

// kc[0..3]=(W1@Wout)[k], kc[4]=b1.Wout, kc[5..8]=W1[k][0], kc[9..12]=W1[k][1],
// kc[13]=b1[0], kc[14]=b1[1], kc[15]=Wout[0], kc[16]=Wout[1], kc[17]=bout[0]
__device__ __forceinline__ void compute_consts(
    const float* __restrict__ W1, const float* __restrict__ b1,
    const float* __restrict__ Wout, const float* __restrict__ bout,
    float* kc, int tid) {
    if (tid < 64) {
        float wj = Wout[tid];
        float p0 = W1[0 * HIDDEN + tid] * wj;
        float p1 = W1[1 * HIDDEN + tid] * wj;
        float p2 = W1[2 * HIDDEN + tid] * wj;
        float p3 = W1[3 * HIDDEN + tid] * wj;
        float pb = b1[tid] * wj;
        #pragma unroll
        for (int off = 32; off > 0; off >>= 1) {
            p0 += __shfl_down(p0, off);
            p1 += __shfl_down(p1, off);
            p2 += __shfl_down(p2, off);
            p3 += __shfl_down(p3, off);
            pb += __shfl_down(pb, off);
        }
        if (tid < 4) {
            kc[5 + tid] = W1[tid * HIDDEN + 0];
            kc[9 + tid] = W1[tid * HIDDEN + 1];
        }
        if (tid == 0) {
            kc[0] = p0; kc[1] = p1; kc[2] = p2; kc[3] = p3; kc[4] = pb;
            kc[13] = b1[0]; kc[14] = b1[1];
            kc[15] = Wout[0]; kc[16] = Wout[1];
            kc[17] = bout[0];
        }
    }
}

__device__ __forceinline__ float contrib(
    float4 xe, float cs, float sn_signed,
    float c0, float c1, float c2, float c3, float cb,
    float a0, float a1, float a2, float a3,
    float g0, float g1, float g2, float g3,
    float b10, float b11, float w0, float w1) {
    float h0 = xe.x * a0 + xe.y * a1 + xe.z * a2 + xe.w * a3 + b10;
    float h1 = xe.x * g0 + xe.y * g1 + xe.z * g2 + xe.w * g3 + b11;
    float d  = xe.x * c0 + xe.y * c1 + xe.z * c2 + xe.w * c3 + cb;
    float a  = h0 * w0 + h1 * w1;
    float b  = h0 * w1 - h1 * w0;
    return cs * a + sn_signed * b + (d - a);
}

// ---- Kernel 1: per edge-pair, dense lanes, no predication. 2M gathers total,
// maximal TLP, coalesced float4 value write.
__global__ __launch_bounds__(B1_THREADS) void edgeval_kernel(
    const int4* __restrict__ epairs, const float2* __restrict__ ppairs,
    const float4* __restrict__ x4,
    const float* __restrict__ W1, const float* __restrict__ b1,
    const float* __restrict__ Wout, const float* __restrict__ bout,
    float4* __restrict__ vals4) {
    __shared__ float kc[18];
    compute_consts(W1, b1, Wout, bout, kc, threadIdx.x);
    __syncthreads();
    int p = blockIdx.x * B1_THREADS + threadIdx.x;
    if (p >= PAIRS) return;

    const float c0 = kc[0], c1 = kc[1], c2 = kc[2], c3 = kc[3], cb = kc[4];
    const float a0 = kc[5], a1 = kc[6], a2 = kc[7], a3 = kc[8];
    const float g0 = kc[9], g1 = kc[10], g2 = kc[11], g3 = kc[12];
    const float b10 = kc[13], b11 = kc[14], w0 = kc[15], w1 = kc[16];

    int4   ee = epairs[p];                 // edge0=(x,y), edge1=(z,w)
    float2 pp = ppairs[p];
    float4 xu0 = x4[ee.x];
    float4 xv0 = x4[ee.y];
    float4 xu1 = x4[ee.z];
    float4 xv1 = x4[ee.w];

    float sn0, cs0, sn1, cs1;
    __sincosf(pp.x, &sn0, &cs0);
    __sincosf(pp.y, &sn1, &cs1);

    // to_v lands on node ee.y (src u); to_u lands on node ee.x (src v)
    float to_v0 = contrib(xu0, cs0,  sn0, c0,c1,c2,c3,cb, a0,a1,a2,a3, g0,g1,g2,g3, b10,b11,w0,w1);
    float to_u0 = contrib(xv0, cs0, -sn0, c0,c1,c2,c3,cb, a0,a1,a2,a3, g0,g1,g2,g3, b10,b11,w0,w1);
    float to_v1 = contrib(xu1, cs1,  sn1, c0,c1,c2,c3,cb, a0,a1,a2,a3, g0,g1,g2,g3, b10,b11,w0,w1);
    float to_u1 = contrib(xv1, cs1, -sn1, c0,c1,c2,c3,cb, a0,a1,a2,a3, g0,g1,g2,g3, b10,b11,w0,w1);

    vals4[p] = make_float4(to_v0, to_u0, to_v1, to_u1);
}

// ---- Kernel 2: pure streaming binner. Block (r,s): coalesced int4+float4
// loads, 4 predicated LDS atomics, no gathers/sincos/cross-lane ops.
// Blocks sharing slice s differ by 64 in blockIdx => same XCD => slice data
// cached once in that XCD's L2.
__global__ __launch_bounds__(B2_THREADS) void range_kernel(
    const int4* __restrict__ epairs, const float4* __restrict__ vals4,
    float* __restrict__ part) {
    __shared__ float bins[C_RANGE];        // 100,352 B
    const int tid = threadIdx.x;
    const int r = blockIdx.x >> 6;
    const int s = blockIdx.x & 63;

    {
        float4 z = make_float4(0.f, 0.f, 0.f, 0.f);
        float4* b4 = (float4*)bins;
        for (int j = tid; j < C_RANGE / 4; j += B2_THREADS) b4[j] = z;
    }
    __syncthreads();

    const int nlo = r * C_RANGE;
    const int pA = s * PPS;
    const int pB = min(pA + PPS, PAIRS);

    #pragma unroll 2
    for (int p = pA + tid; p < pB; p += B2_THREADS) {
        int4   ee = epairs[p];
        float4 vv = vals4[p];
        unsigned jv0 = (unsigned)(ee.y - nlo);
        unsigned ju0 = (unsigned)(ee.x - nlo);
        unsigned jv1 = (unsigned)(ee.w - nlo);
        unsigned ju1 = (unsigned)(ee.z - nlo);
        if (jv0 < C_RANGE) atomicAdd(&bins[jv0], vv.x);
        if (ju0 < C_RANGE) atomicAdd(&bins[ju0], vv.y);
        if (jv1 < C_RANGE) atomicAdd(&bins[jv1], vv.z);
        if (ju1 < C_RANGE) atomicAdd(&bins[ju1], vv.w);
    }
    __syncthreads();

    float4* __restrict__ d4 = (float4*)(part + (size_t)blockIdx.x * C_RANGE);
    const float4* b4 = (const float4*)bins;
    for (int j = tid; j < C_RANGE / 4; j += B2_THREADS) d4[j] = b4[j];
}

// ---- Kernel 3: out[i] = sum_s part[(r,s)][j] + x_i.(W1@Wout) + b1.Wout + bout
__global__ __launch_bounds__(512) void reduce_kernel(
    const float4* __restrict__ x4,
    const float* __restrict__ W1, const float* __restrict__ b1,
    const float* __restrict__ Wout, const float* __restrict__ bout,
    const float* __restrict__ part, float* __restrict__ out) {
    __shared__ float kc[18];
    compute_consts(W1, b1, Wout, bout, kc, threadIdx.x);
    __syncthreads();
    int i = blockIdx.x * 512 + threadIdx.x;
    if (i >= N_NODES) return;
    int r = i / C_RANGE;
    int j = i - r * C_RANGE;
    const float* __restrict__ p = part + ((size_t)(r * N_SLICES)) * C_RANGE + j;
    float sum = 0.0f;
    #pragma unroll 16
    for (int s = 0; s < N_SLICES; s++) sum += p[(size_t)s * C_RANGE];
    float4 xi = x4[i];
    out[i] = sum + xi.x * kc[0] + xi.y * kc[1] + xi.z * kc[2] + xi.w * kc[3]
           + kc[4] + kc[17];
}

// ---- Fallback (ws too small): direct device atomics ----------------------
__global__ void precompute_kernel(const float* __restrict__ W1,
                                  const float* __restrict__ b1,
                                  const float* __restrict__ Wout,
                                  const float* __restrict__ bout,
                                  float* __restrict__ consts) {
    __shared__ float kc[18];
    compute_consts(W1, b1, Wout, bout, kc, threadIdx.x);
    __syncthreads();
    if (threadIdx.x < 18) consts[threadIdx.x] = kc[threadIdx.x];
}

__global__ void edge_atomic_kernel(const int2* __restrict__ edges,
                                   const float* __restrict__ phases,
                                   const float4* __restrict__ x4,
                                   const float* __restrict__ consts,
                                   float* __restrict__ rep) {
    int e = blockIdx.x * blockDim.x + threadIdx.x;
    if (e >= N_EDGES) return;
    float c0 = consts[0], c1 = consts[1], c2 = consts[2], c3 = consts[3];
    float cb = consts[4];
    float a0 = consts[5], a1 = consts[6], a2 = consts[7], a3 = consts[8];
    float g0 = consts[9], g1 = consts[10], g2 = consts[11], g3 = consts[12];
    float b10 = consts[13], b11 = consts[14], w0 = consts[15], w1 = consts[16];
    int2 ed = edges[e];
    float ph = phases[e];
    float sn, cs;
    __sincosf(ph, &sn, &cs);
    float4 xu = x4[ed.x];
    float4 xv = x4[ed.y];
    atomicAdd(rep + ed.y, contrib(xu, cs,  sn, c0,c1,c2,c3,cb, a0,a1,a2,a3, g0,g1,g2,g3, b10,b11,w0,w1));
    atomicAdd(rep + ed.x, contrib(xv, cs, -sn, c0,c1,c2,c3,cb, a0,a1,a2,a3, g0,g1,g2,g3, b10,b11,w0,w1));
}

__global__ void final_kernel(const float4* __restrict__ x4,
                             const float* __restrict__ consts,
                             const float* __restrict__ rep,
                             float* __restrict__ out) {
    int i = blockIdx.x * blockDim.x + threadIdx.x;
    if (i >= N_NODES) return;
    float4 xi = x4[i];
    out[i] = rep[i] + xi.x * consts[0] + xi.y * consts[1] + xi.z * consts[2]
           + xi.w * consts[3] + consts[4] + consts[17];
}

extern "C" void kernel_launch(void* const* d_in, const int* in_sizes, int n_in,
                              void* d_out, int out_size, void* d_ws, size_t ws_size,
                              hipStream_t stream) {
    const float* x      = (const float*)d_in[0];
    const int*   edges  = (const int*)d_in[1];
    const float* W1     = (const float*)d_in[2];
    const float* b1     = (const float*)d_in[3];
    const float* phases = (const float*)d_in[4];
    const float* Wout   = (const float*)d_in[5];
    const float* bout   = (const float*)d_in[6];
    float* out = (float*)d_out;

    const size_t vals_bytes = (size_t)PAIRS * sizeof(float4);            // 8 MB
    const size_t part_off   = (vals_bytes + 255) & ~(size_t)255;
    const size_t part_bytes =
        (size_t)N_RANGES * N_SLICES * C_RANGE * sizeof(float);           // ~25.7 MB

    if (ws_size >= part_off + part_bytes) {
        float4* vals4 = (float4*)d_ws;
        float*  part  = (float*)((char*)d_ws + part_off);
        edgeval_kernel<<<(PAIRS + B1_THREADS - 1) / B1_THREADS, B1_THREADS, 0, stream>>>(
            (const int4*)edges, (const float2*)phases, (const float4*)x,
            W1, b1, Wout, bout, vals4);
        range_kernel<<<N_RANGES * N_SLICES, B2_THREADS, 0, stream>>>(
            (const int4*)edges, vals4, part);
        reduce_kernel<<<(N_NODES + 511) / 512, 512, 0, stream>>>(
            (const float4*)x, W1, b1, Wout, bout, part, out);
    } else {
        float* consts = (float*)d_ws;
        float* rep    = (float*)((char*)d_ws + 256);
        hipMemsetAsync(rep, 0, N_NODES * sizeof(float), stream);
        precompute_kernel<<<1, 64, 0, stream>>>(W1, b1, Wout, bout, consts);
        edge_atomic_kernel<<<(N_EDGES + 255) / 256, 256, 0, stream>>>(
            (const int2*)edges, phases, (const float4*)x, consts, rep);
        final_kernel<<<(N_NODES + 255) / 256, 256, 0, stream>>>(
            (const float4*)x, consts, rep, out);
    }
}

// Round 11
// 101.032 us; speedup vs baseline: 1.0613x; 1.0613x over previous
//
#include <hip/hip_runtime.h>

#define N_NODES 100000
#define N_EDGES 1000000
#define HIDDEN 64

// ---- range-pass geometry ----
#define N_RANGES 3
#define C_RANGE 33344                    // 3*33344 = 100,032 >= 100,000; bins 133,376 B LDS
#define N_SLICES 85                      // 3*85 = 255 blocks -> exactly 1 block/CU
#define PAIRS (N_EDGES / 2)              // 500,000 edge pairs
#define PPB ((PAIRS + N_SLICES - 1) / N_SLICES)   // 5883 pairs per slice
#define A_THREADS 1024                   // 16 waves in the single resident block

// kc[0..3]=(W1@Wout)[k], kc[4]=b1.Wout, kc[5..8]=W1[k][0], kc[9..12]=W1[k][1],
// kc[13]=b1[0], kc[14]=b1[1], kc[15]=Wout[0], kc[16]=Wout[1], kc[17]=bout[0]
__device__ __forceinline__ void compute_consts(
    const float* __restrict__ W1, const float* __restrict__ b1,
    const float* __restrict__ Wout, const float* __restrict__ bout,
    float* kc, int tid) {
    if (tid < 64) {
        float wj = Wout[tid];
        float p0 = W1[0 * HIDDEN + tid] * wj;
        float p1 = W1[1 * HIDDEN + tid] * wj;
        float p2 = W1[2 * HIDDEN + tid] * wj;
        float p3 = W1[3 * HIDDEN + tid] * wj;
        float pb = b1[tid] * wj;
        #pragma unroll
        for (int off = 32; off > 0; off >>= 1) {
            p0 += __shfl_down(p0, off);
            p1 += __shfl_down(p1, off);
            p2 += __shfl_down(p2, off);
            p3 += __shfl_down(p3, off);
            pb += __shfl_down(pb, off);
        }
        if (tid < 4) {
            kc[5 + tid] = W1[tid * HIDDEN + 0];
            kc[9 + tid] = W1[tid * HIDDEN + 1];
        }
        if (tid == 0) {
            kc[0] = p0; kc[1] = p1; kc[2] = p2; kc[3] = p3; kc[4] = pb;
            kc[13] = b1[0]; kc[14] = b1[1];
            kc[15] = Wout[0]; kc[16] = Wout[1];
            kc[17] = bout[0];
        }
    }
}

__device__ __forceinline__ float contrib(
    float4 xe, float cs, float sn_signed,
    float c0, float c1, float c2, float c3, float cb,
    float a0, float a1, float a2, float a3,
    float g0, float g1, float g2, float g3,
    float b10, float b11, float w0, float w1) {
    float h0 = xe.x * a0 + xe.y * a1 + xe.z * a2 + xe.w * a3 + b10;
    float h1 = xe.x * g0 + xe.y * g1 + xe.z * g2 + xe.w * g3 + b11;
    float d  = xe.x * c0 + xe.y * c1 + xe.z * c2 + xe.w * c3 + cb;
    float a  = h0 * w0 + h1 * w1;
    float b  = h0 * w1 - h1 * w0;
    return cs * a + sn_signed * b + (d - a);
}

// ---- Kernel A: r8's proven single-basic-block loop (paired edge loads,
// address-clamped unconditional gathers, predicated LDS atomics), with
// redundancy cut 7->3 ranges via 133 KB LDS bins (1 block/CU, 16 waves).
__global__ __launch_bounds__(A_THREADS) void range_kernel(
    const int2* __restrict__ edges, const float* __restrict__ phases,
    const float4* __restrict__ x4,
    const float* __restrict__ W1, const float* __restrict__ b1,
    const float* __restrict__ Wout, const float* __restrict__ bout,
    float* __restrict__ part) {
    __shared__ float bins[C_RANGE];         // 133,376 B
    __shared__ float kc[18];
    const int tid = threadIdx.x;
    const int r = blockIdx.x / N_SLICES;
    const int s = blockIdx.x % N_SLICES;

    compute_consts(W1, b1, Wout, bout, kc, tid);
    {   // vectorized zero: C_RANGE/4 = 8336 float4 slots
        float4 z = make_float4(0.f, 0.f, 0.f, 0.f);
        float4* b4 = (float4*)bins;
        for (int j = tid; j < C_RANGE / 4; j += A_THREADS) b4[j] = z;
    }
    __syncthreads();

    const float c0 = kc[0], c1 = kc[1], c2 = kc[2], c3 = kc[3], cb = kc[4];
    const float a0 = kc[5], a1 = kc[6], a2 = kc[7], a3 = kc[8];
    const float g0 = kc[9], g1 = kc[10], g2 = kc[11], g3 = kc[12];
    const float b10 = kc[13], b11 = kc[14], w0 = kc[15], w1 = kc[16];

    const int nlo = r * C_RANGE;
    const int pA = s * PPB;
    const int pB = min(pA + PPB, PAIRS);
    const int4*   __restrict__ epairs = (const int4*)edges;
    const float2* __restrict__ ppairs = (const float2*)phases;

    #pragma unroll 2
    for (int p = pA + tid; p < pB; p += A_THREADS) {
        int4   ee = epairs[p];                 // edge0=(x,y), edge1=(z,w)
        float2 pp = ppairs[p];

        unsigned jv0 = (unsigned)(ee.y - nlo); // dest v0, src u0
        unsigned ju0 = (unsigned)(ee.x - nlo); // dest u0, src v0
        unsigned jv1 = (unsigned)(ee.w - nlo);
        unsigned ju1 = (unsigned)(ee.z - nlo);
        bool pv0 = jv0 < C_RANGE, pu0 = ju0 < C_RANGE;
        bool pv1 = jv1 < C_RANGE, pu1 = ju1 < C_RANGE;

        // clamped gathers — always issued, single basic block
        float4 xsv0 = x4[pv0 ? ee.x : 0];
        float4 xsu0 = x4[pu0 ? ee.y : 0];
        float4 xsv1 = x4[pv1 ? ee.z : 0];
        float4 xsu1 = x4[pu1 ? ee.w : 0];

        float sn0, cs0, sn1, cs1;
        __sincosf(pp.x, &sn0, &cs0);
        __sincosf(pp.y, &sn1, &cs1);

        float tv0 = contrib(xsv0, cs0,  sn0, c0,c1,c2,c3,cb, a0,a1,a2,a3, g0,g1,g2,g3, b10,b11,w0,w1);
        float tu0 = contrib(xsu0, cs0, -sn0, c0,c1,c2,c3,cb, a0,a1,a2,a3, g0,g1,g2,g3, b10,b11,w0,w1);
        float tv1 = contrib(xsv1, cs1,  sn1, c0,c1,c2,c3,cb, a0,a1,a2,a3, g0,g1,g2,g3, b10,b11,w0,w1);
        float tu1 = contrib(xsu1, cs1, -sn1, c0,c1,c2,c3,cb, a0,a1,a2,a3, g0,g1,g2,g3, b10,b11,w0,w1);

        if (pv0) atomicAdd(&bins[jv0], tv0);
        if (pu0) atomicAdd(&bins[ju0], tu0);
        if (pv1) atomicAdd(&bins[jv1], tv1);
        if (pu1) atomicAdd(&bins[ju1], tu1);
    }
    __syncthreads();

    // vectorized flush
    float4* __restrict__ d4 = (float4*)(part + (size_t)blockIdx.x * C_RANGE);
    const float4* b4 = (const float4*)bins;
    for (int j = tid; j < C_RANGE / 4; j += A_THREADS) d4[j] = b4[j];
}

// ---- Kernel B: out[i] = sum_s part[(r,s)][j] + x_i.(W1@Wout) + b1.Wout + bout
__global__ __launch_bounds__(512) void reduce_kernel(
    const float4* __restrict__ x4,
    const float* __restrict__ W1, const float* __restrict__ b1,
    const float* __restrict__ Wout, const float* __restrict__ bout,
    const float* __restrict__ part, float* __restrict__ out) {
    __shared__ float kc[18];
    compute_consts(W1, b1, Wout, bout, kc, threadIdx.x);
    __syncthreads();
    int i = blockIdx.x * 512 + threadIdx.x;
    if (i >= N_NODES) return;
    int r = i / C_RANGE;                 // compile-time magic-mul
    int j = i - r * C_RANGE;
    const float* __restrict__ p = part + ((size_t)(r * N_SLICES)) * C_RANGE + j;
    float sum = 0.0f;
    #pragma unroll 5
    for (int s = 0; s < N_SLICES; s++) sum += p[(size_t)s * C_RANGE];
    float4 xi = x4[i];
    out[i] = sum + xi.x * kc[0] + xi.y * kc[1] + xi.z * kc[2] + xi.w * kc[3]
           + kc[4] + kc[17];
}

// ---- Fallback (ws too small): direct device atomics ----------------------
__global__ void precompute_kernel(const float* __restrict__ W1,
                                  const float* __restrict__ b1,
                                  const float* __restrict__ Wout,
                                  const float* __restrict__ bout,
                                  float* __restrict__ consts) {
    __shared__ float kc[18];
    compute_consts(W1, b1, Wout, bout, kc, threadIdx.x);
    __syncthreads();
    if (threadIdx.x < 18) consts[threadIdx.x] = kc[threadIdx.x];
}

__global__ void edge_atomic_kernel(const int2* __restrict__ edges,
                                   const float* __restrict__ phases,
                                   const float4* __restrict__ x4,
                                   const float* __restrict__ consts,
                                   float* __restrict__ rep) {
    int e = blockIdx.x * blockDim.x + threadIdx.x;
    if (e >= N_EDGES) return;
    float c0 = consts[0], c1 = consts[1], c2 = consts[2], c3 = consts[3];
    float cb = consts[4];
    float a0 = consts[5], a1 = consts[6], a2 = consts[7], a3 = consts[8];
    float g0 = consts[9], g1 = consts[10], g2 = consts[11], g3 = consts[12];
    float b10 = consts[13], b11 = consts[14], w0 = consts[15], w1 = consts[16];
    int2 ed = edges[e];
    float ph = phases[e];
    float sn, cs;
    __sincosf(ph, &sn, &cs);
    float4 xu = x4[ed.x];
    float4 xv = x4[ed.y];
    atomicAdd(rep + ed.y, contrib(xu, cs,  sn, c0,c1,c2,c3,cb, a0,a1,a2,a3, g0,g1,g2,g3, b10,b11,w0,w1));
    atomicAdd(rep + ed.x, contrib(xv, cs, -sn, c0,c1,c2,c3,cb, a0,a1,a2,a3, g0,g1,g2,g3, b10,b11,w0,w1));
}

__global__ void final_kernel(const float4* __restrict__ x4,
                             const float* __restrict__ consts,
                             const float* __restrict__ rep,
                             float* __restrict__ out) {
    int i = blockIdx.x * blockDim.x + threadIdx.x;
    if (i >= N_NODES) return;
    float4 xi = x4[i];
    out[i] = rep[i] + xi.x * consts[0] + xi.y * consts[1] + xi.z * consts[2]
           + xi.w * consts[3] + consts[4] + consts[17];
}

extern "C" void kernel_launch(void* const* d_in, const int* in_sizes, int n_in,
                              void* d_out, int out_size, void* d_ws, size_t ws_size,
                              hipStream_t stream) {
    const float* x      = (const float*)d_in[0];
    const int*   edges  = (const int*)d_in[1];
    const float* W1     = (const float*)d_in[2];
    const float* b1     = (const float*)d_in[3];
    const float* phases = (const float*)d_in[4];
    const float* Wout   = (const float*)d_in[5];
    const float* bout   = (const float*)d_in[6];
    float* out = (float*)d_out;

    const size_t part_bytes =
        (size_t)N_RANGES * N_SLICES * C_RANGE * sizeof(float);   // ~34 MB

    if (ws_size >= part_bytes) {
        float* part = (float*)d_ws;
        // No memset needed: every part slot is written by exactly one block.
        range_kernel<<<N_RANGES * N_SLICES, A_THREADS, 0, stream>>>(
            (const int2*)edges, phases, (const float4*)x,
            W1, b1, Wout, bout, part);
        reduce_kernel<<<(N_NODES + 511) / 512, 512, 0, stream>>>(
            (const float4*)x, W1, b1, Wout, bout, part, out);
    } else {
        float* consts = (float*)d_ws;
        float* rep    = (float*)((char*)d_ws + 256);
        hipMemsetAsync(rep, 0, N_NODES * sizeof(float), stream);
        precompute_kernel<<<1, 64, 0, stream>>>(W1, b1, Wout, bout, consts);
        edge_atomic_kernel<<<(N_EDGES + 255) / 256, 256, 0, stream>>>(
            (const int2*)edges, phases, (const float4*)x, consts, rep);
        final_kernel<<<(N_NODES + 255) / 256, 256, 0, stream>>>(
            (const float4*)x, consts, rep, out);
    }
}

// Round 12
// 98.711 us; speedup vs baseline: 1.0862x; 1.0235x over previous
//
#include <hip/hip_runtime.h>
#include <hip/hip_fp16.h>

#define N_NODES 100000
#define N_EDGES 1000000
#define HIDDEN 64

// ---- range-pass geometry ----
#define N_RANGES 3
#define C_RANGE 33344                    // 3*33344 = 100,032 >= 100,000; bins 133,376 B LDS
#define N_SLICES 85                      // 3*85 = 255 blocks -> exactly 1 block/CU
#define PAIRS (N_EDGES / 2)              // 500,000 edge pairs
#define PPB ((PAIRS + N_SLICES - 1) / N_SLICES)   // 5883 pairs per slice
#define A_THREADS 1024                   // 16 waves in the single resident block

// kc[0..3]=(W1@Wout)[k], kc[4]=b1.Wout, kc[5..8]=W1[k][0], kc[9..12]=W1[k][1],
// kc[13]=b1[0], kc[14]=b1[1], kc[15]=Wout[0], kc[16]=Wout[1], kc[17]=bout[0]
__device__ __forceinline__ void compute_consts(
    const float* __restrict__ W1, const float* __restrict__ b1,
    const float* __restrict__ Wout, const float* __restrict__ bout,
    float* kc, int tid) {
    if (tid < 64) {
        float wj = Wout[tid];
        float p0 = W1[0 * HIDDEN + tid] * wj;
        float p1 = W1[1 * HIDDEN + tid] * wj;
        float p2 = W1[2 * HIDDEN + tid] * wj;
        float p3 = W1[3 * HIDDEN + tid] * wj;
        float pb = b1[tid] * wj;
        #pragma unroll
        for (int off = 32; off > 0; off >>= 1) {
            p0 += __shfl_down(p0, off);
            p1 += __shfl_down(p1, off);
            p2 += __shfl_down(p2, off);
            p3 += __shfl_down(p3, off);
            pb += __shfl_down(pb, off);
        }
        if (tid < 4) {
            kc[5 + tid] = W1[tid * HIDDEN + 0];
            kc[9 + tid] = W1[tid * HIDDEN + 1];
        }
        if (tid == 0) {
            kc[0] = p0; kc[1] = p1; kc[2] = p2; kc[3] = p3; kc[4] = pb;
            kc[13] = b1[0]; kc[14] = b1[1];
            kc[15] = Wout[0]; kc[16] = Wout[1];
            kc[17] = bout[0];
        }
    }
}

__device__ __forceinline__ float contrib(
    float4 xe, float cs, float sn_signed,
    float c0, float c1, float c2, float c3, float cb,
    float a0, float a1, float a2, float a3,
    float g0, float g1, float g2, float g3,
    float b10, float b11, float w0, float w1) {
    float h0 = xe.x * a0 + xe.y * a1 + xe.z * a2 + xe.w * a3 + b10;
    float h1 = xe.x * g0 + xe.y * g1 + xe.z * g2 + xe.w * g3 + b11;
    float d  = xe.x * c0 + xe.y * c1 + xe.z * c2 + xe.w * c3 + cb;
    float a  = h0 * w0 + h1 * w1;
    float b  = h0 * w1 - h1 * w0;
    return cs * a + sn_signed * b + (d - a);
}

__device__ __forceinline__ unsigned pack_half2(float x, float y) {
    __half2 h = __floats2half2_rn(x, y);
    return *(unsigned*)&h;
}

// ---- Kernel A: r11's proven loop; flush converts bins to fp16 (packed) ----
__global__ __launch_bounds__(A_THREADS) void range_kernel(
    const int2* __restrict__ edges, const float* __restrict__ phases,
    const float4* __restrict__ x4,
    const float* __restrict__ W1, const float* __restrict__ b1,
    const float* __restrict__ Wout, const float* __restrict__ bout,
    __half* __restrict__ part) {
    __shared__ float bins[C_RANGE];         // 133,376 B
    __shared__ float kc[18];
    const int tid = threadIdx.x;
    const int r = blockIdx.x / N_SLICES;
    const int s = blockIdx.x % N_SLICES;

    compute_consts(W1, b1, Wout, bout, kc, tid);
    {   // vectorized zero: C_RANGE/4 = 8336 float4 slots
        float4 z = make_float4(0.f, 0.f, 0.f, 0.f);
        float4* b4 = (float4*)bins;
        for (int j = tid; j < C_RANGE / 4; j += A_THREADS) b4[j] = z;
    }
    __syncthreads();

    const float c0 = kc[0], c1 = kc[1], c2 = kc[2], c3 = kc[3], cb = kc[4];
    const float a0 = kc[5], a1 = kc[6], a2 = kc[7], a3 = kc[8];
    const float g0 = kc[9], g1 = kc[10], g2 = kc[11], g3 = kc[12];
    const float b10 = kc[13], b11 = kc[14], w0 = kc[15], w1 = kc[16];

    const int nlo = r * C_RANGE;
    const int pA = s * PPB;
    const int pB = min(pA + PPB, PAIRS);
    const int4*   __restrict__ epairs = (const int4*)edges;
    const float2* __restrict__ ppairs = (const float2*)phases;

    #pragma unroll 2
    for (int p = pA + tid; p < pB; p += A_THREADS) {
        int4   ee = epairs[p];                 // edge0=(x,y), edge1=(z,w)
        float2 pp = ppairs[p];

        unsigned jv0 = (unsigned)(ee.y - nlo); // dest v0, src u0
        unsigned ju0 = (unsigned)(ee.x - nlo); // dest u0, src v0
        unsigned jv1 = (unsigned)(ee.w - nlo);
        unsigned ju1 = (unsigned)(ee.z - nlo);
        bool pv0 = jv0 < C_RANGE, pu0 = ju0 < C_RANGE;
        bool pv1 = jv1 < C_RANGE, pu1 = ju1 < C_RANGE;

        // clamped gathers — always issued, single basic block
        float4 xsv0 = x4[pv0 ? ee.x : 0];
        float4 xsu0 = x4[pu0 ? ee.y : 0];
        float4 xsv1 = x4[pv1 ? ee.z : 0];
        float4 xsu1 = x4[pu1 ? ee.w : 0];

        float sn0, cs0, sn1, cs1;
        __sincosf(pp.x, &sn0, &cs0);
        __sincosf(pp.y, &sn1, &cs1);

        float tv0 = contrib(xsv0, cs0,  sn0, c0,c1,c2,c3,cb, a0,a1,a2,a3, g0,g1,g2,g3, b10,b11,w0,w1);
        float tu0 = contrib(xsu0, cs0, -sn0, c0,c1,c2,c3,cb, a0,a1,a2,a3, g0,g1,g2,g3, b10,b11,w0,w1);
        float tv1 = contrib(xsv1, cs1,  sn1, c0,c1,c2,c3,cb, a0,a1,a2,a3, g0,g1,g2,g3, b10,b11,w0,w1);
        float tu1 = contrib(xsu1, cs1, -sn1, c0,c1,c2,c3,cb, a0,a1,a2,a3, g0,g1,g2,g3, b10,b11,w0,w1);

        if (pv0) atomicAdd(&bins[jv0], tv0);
        if (pu0) atomicAdd(&bins[ju0], tu0);
        if (pv1) atomicAdd(&bins[jv1], tv1);
        if (pu1) atomicAdd(&bins[ju1], tu1);
    }
    __syncthreads();

    // fp16 flush: 4 bins -> uint2 (8 B) per thread-iter, coalesced
    uint2* __restrict__ d2 = (uint2*)(part + (size_t)blockIdx.x * C_RANGE);
    const float4* b4 = (const float4*)bins;
    for (int j = tid; j < C_RANGE / 4; j += A_THREADS) {
        float4 v = b4[j];
        d2[j] = make_uint2(pack_half2(v.x, v.y), pack_half2(v.z, v.w));
    }
}

// ---- Kernel B: out[i] = sum_s fp16 part[(r,s)][j] + x_i.(W1@Wout) + b1.Wout + bout
__global__ __launch_bounds__(512) void reduce_kernel(
    const float4* __restrict__ x4,
    const float* __restrict__ W1, const float* __restrict__ b1,
    const float* __restrict__ Wout, const float* __restrict__ bout,
    const __half* __restrict__ part, float* __restrict__ out) {
    __shared__ float kc[18];
    compute_consts(W1, b1, Wout, bout, kc, threadIdx.x);
    __syncthreads();
    int i = blockIdx.x * 512 + threadIdx.x;
    if (i >= N_NODES) return;
    int r = i / C_RANGE;                 // compile-time magic-mul
    int j = i - r * C_RANGE;
    const __half* __restrict__ p = part + ((size_t)(r * N_SLICES)) * C_RANGE + j;
    float sum = 0.0f;
    #pragma unroll 5
    for (int s = 0; s < N_SLICES; s++) sum += __half2float(p[(size_t)s * C_RANGE]);
    float4 xi = x4[i];
    out[i] = sum + xi.x * kc[0] + xi.y * kc[1] + xi.z * kc[2] + xi.w * kc[3]
           + kc[4] + kc[17];
}

// ---- Fallback (ws too small): direct device atomics ----------------------
__global__ void precompute_kernel(const float* __restrict__ W1,
                                  const float* __restrict__ b1,
                                  const float* __restrict__ Wout,
                                  const float* __restrict__ bout,
                                  float* __restrict__ consts) {
    __shared__ float kc[18];
    compute_consts(W1, b1, Wout, bout, kc, threadIdx.x);
    __syncthreads();
    if (threadIdx.x < 18) consts[threadIdx.x] = kc[threadIdx.x];
}

__global__ void edge_atomic_kernel(const int2* __restrict__ edges,
                                   const float* __restrict__ phases,
                                   const float4* __restrict__ x4,
                                   const float* __restrict__ consts,
                                   float* __restrict__ rep) {
    int e = blockIdx.x * blockDim.x + threadIdx.x;
    if (e >= N_EDGES) return;
    float c0 = consts[0], c1 = consts[1], c2 = consts[2], c3 = consts[3];
    float cb = consts[4];
    float a0 = consts[5], a1 = consts[6], a2 = consts[7], a3 = consts[8];
    float g0 = consts[9], g1 = consts[10], g2 = consts[11], g3 = consts[12];
    float b10 = consts[13], b11 = consts[14], w0 = consts[15], w1 = consts[16];
    int2 ed = edges[e];
    float ph = phases[e];
    float sn, cs;
    __sincosf(ph, &sn, &cs);
    float4 xu = x4[ed.x];
    float4 xv = x4[ed.y];
    atomicAdd(rep + ed.y, contrib(xu, cs,  sn, c0,c1,c2,c3,cb, a0,a1,a2,a3, g0,g1,g2,g3, b10,b11,w0,w1));
    atomicAdd(rep + ed.x, contrib(xv, cs, -sn, c0,c1,c2,c3,cb, a0,a1,a2,a3, g0,g1,g2,g3, b10,b11,w0,w1));
}

__global__ void final_kernel(const float4* __restrict__ x4,
                             const float* __restrict__ consts,
                             const float* __restrict__ rep,
                             float* __restrict__ out) {
    int i = blockIdx.x * blockDim.x + threadIdx.x;
    if (i >= N_NODES) return;
    float4 xi = x4[i];
    out[i] = rep[i] + xi.x * consts[0] + xi.y * consts[1] + xi.z * consts[2]
           + xi.w * consts[3] + consts[4] + consts[17];
}

extern "C" void kernel_launch(void* const* d_in, const int* in_sizes, int n_in,
                              void* d_out, int out_size, void* d_ws, size_t ws_size,
                              hipStream_t stream) {
    const float* x      = (const float*)d_in[0];
    const int*   edges  = (const int*)d_in[1];
    const float* W1     = (const float*)d_in[2];
    const float* b1     = (const float*)d_in[3];
    const float* phases = (const float*)d_in[4];
    const float* Wout   = (const float*)d_in[5];
    const float* bout   = (const float*)d_in[6];
    float* out = (float*)d_out;

    const size_t part_bytes =
        (size_t)N_RANGES * N_SLICES * C_RANGE * sizeof(__half);   // ~17 MB

    if (ws_size >= part_bytes) {
        __half* part = (__half*)d_ws;
        // No memset needed: every part slot is written by exactly one block.
        range_kernel<<<N_RANGES * N_SLICES, A_THREADS, 0, stream>>>(
            (const int2*)edges, phases, (const float4*)x,
            W1, b1, Wout, bout, part);
        reduce_kernel<<<(N_NODES + 511) / 512, 512, 0, stream>>>(
            (const float4*)x, W1, b1, Wout, bout, part, out);
    } else {
        float* consts = (float*)d_ws;
        float* rep    = (float*)((char*)d_ws + 256);
        hipMemsetAsync(rep, 0, N_NODES * sizeof(float), stream);
        precompute_kernel<<<1, 64, 0, stream>>>(W1, b1, Wout, bout, consts);
        edge_atomic_kernel<<<(N_EDGES + 255) / 256, 256, 0, stream>>>(
            (const int2*)edges, phases, (const float4*)x, consts, rep);
        final_kernel<<<(N_NODES + 255) / 256, 256, 0, stream>>>(
            (const float4*)x, consts, rep, out);
    }
}